// Round 8
// baseline (119.485 us; speedup 1.0000x reference)
//
#include <hip/hip_runtime.h>

// Problem constants (from reference):
//   x:    [32, 64, 256, 256] fp32
//   coef: [64,1,1] fp32, bias: [64,1,1] fp32 (zeros)
//   out:  [32, 64, 128, 128] fp32
// out[b,c,ho,wo] = coef[c] * sum_{c'} sum_{2x2} x[b,c',2ho+dh,2wo+dw] + bias[c]
//
// Two-pass split:
//   pass 1: x (512 MiB, NT loads) -> G=4 channel-group partials in d_ws
//           (2048 blocks = 32 waves/CU, max occupancy -> max loads in flight)
//   pass 2: grid-stride broadcast (slab-sequential NT writes), summing the
//           4 L2-resident partials.
// Ladder: 138.0 (fused) -> 128.6 (NT) -> 122.4 (2-row) -> 113.8 (2-pass)
//         -> 109.7 (G=2). This round: G=4.

constexpr int B  = 32;
constexpr int C  = 64;
constexpr int H  = 256;
constexpr int W  = 256;
constexpr int HO = 128;
constexpr int WO = 128;

constexpr int G   = 4;       // channel groups for pass 1
constexpr int CPG = C / G;   // 16 channels per group

typedef float floatx4 __attribute__((ext_vector_type(4)));

// -------- Pass 1 (split): channel-group sum + 2x2 pool (pure read) ---------
__global__ __launch_bounds__(256) void pool_reduce_split_kernel(
    const float* __restrict__ x,
    float* __restrict__ pooled)   // [G][B, HO, WO]
{
    // Thread handles a 2x2 block of pooled pixels for ONE channel group.
    const int WO2 = WO / 2;   // 64
    const int HG  = HO / 2;   // 64

    int t    = blockIdx.x * blockDim.x + threadIdx.x;
    int wp   = t % WO2;
    int tmp  = t / WO2;       // hg + HG*(g + G*b)
    int hg   = tmp % HG;
    int tmp2 = tmp / HG;
    int g    = tmp2 % G;
    int b    = tmp2 / G;
    if (b >= B) return;

    const float* xb = x + (size_t)b * C * H * W + (size_t)(g * CPG) * H * W
                        + (size_t)(4 * hg) * W + 4 * wp;

    float s00 = 0.f, s01 = 0.f;
    float s10 = 0.f, s11 = 0.f;
    #pragma unroll 4
    for (int c = 0; c < CPG; ++c) {
        const float* xc = xb + (size_t)c * (H * W);
        floatx4 r0 = __builtin_nontemporal_load(reinterpret_cast<const floatx4*>(xc));
        floatx4 r1 = __builtin_nontemporal_load(reinterpret_cast<const floatx4*>(xc + W));
        floatx4 r2 = __builtin_nontemporal_load(reinterpret_cast<const floatx4*>(xc + 2 * W));
        floatx4 r3 = __builtin_nontemporal_load(reinterpret_cast<const floatx4*>(xc + 3 * W));
        s00 += (r0.x + r0.y) + (r1.x + r1.y);
        s01 += (r0.z + r0.w) + (r1.z + r1.w);
        s10 += (r2.x + r2.y) + (r3.x + r3.y);
        s11 += (r2.z + r2.w) + (r3.z + r3.w);
    }

    float* pb = pooled + (size_t)g * B * HO * WO + (size_t)b * HO * WO
                       + (size_t)(2 * hg) * WO + 2 * wp;
    *reinterpret_cast<float2*>(pb)      = make_float2(s00, s01);
    *reinterpret_cast<float2*>(pb + WO) = make_float2(s10, s11);
}

// -------- Pass 2: grid-stride broadcast + affine (pure write) --------------
__global__ __launch_bounds__(256) void broadcast_affine4_kernel(
    const float* __restrict__ pooled,  // [G][B, HO, WO], L2/L3-resident
    const float* __restrict__ coef,
    const float* __restrict__ bias,
    float* __restrict__ out)           // [B, C, HO, WO]
{
    // Flat vec index i maps exactly to out layout; each grid-stride sweep
    // writes a contiguous slab of out (slab-sequential DRAM writes).
    const size_t nvec   = (size_t)B * C * HO * (WO / 4);    // 8,388,608
    const size_t stride = (size_t)gridDim.x * blockDim.x;
    const size_t pplane = (size_t)B * HO * WO;

    for (size_t i = blockIdx.x * (size_t)blockDim.x + threadIdx.x;
         i < nvec; i += stride) {
        int wq = (int)(i & 31);          // WO/4 = 32
        int ho = (int)((i >> 5) & 127);  // HO = 128
        int c  = (int)((i >> 12) & 63);  // C = 64
        int b  = (int)(i >> 18);

        size_t sp = ((size_t)b * HO + ho) * WO + wq * 4;
        floatx4 p0 = *reinterpret_cast<const floatx4*>(pooled + sp);
        floatx4 p1 = *reinterpret_cast<const floatx4*>(pooled + pplane + sp);
        floatx4 p2 = *reinterpret_cast<const floatx4*>(pooled + 2 * pplane + sp);
        floatx4 p3 = *reinterpret_cast<const floatx4*>(pooled + 3 * pplane + sp);
        float k  = coef[c];
        float bs = bias[c];
        floatx4 v;
        v.x = fmaf((p0.x + p1.x) + (p2.x + p3.x), k, bs);
        v.y = fmaf((p0.y + p1.y) + (p2.y + p3.y), k, bs);
        v.z = fmaf((p0.z + p1.z) + (p2.z + p3.z), k, bs);
        v.w = fmaf((p0.w + p1.w) + (p2.w + p3.w), k, bs);
        __builtin_nontemporal_store(v, reinterpret_cast<floatx4*>(out + i * 4));
    }
}

// -------- R5 single-buffer path (if ws in [2 MiB, 8 MiB)) ------------------
__global__ __launch_bounds__(256) void pool_reduce_kernel(
    const float* __restrict__ x,
    float* __restrict__ pooled)   // [B, HO, WO]
{
    const int WO2 = WO / 2;
    const int HG  = HO / 2;
    int t   = blockIdx.x * blockDim.x + threadIdx.x;
    int wp  = t % WO2;
    int tmp = t / WO2;
    int hg  = tmp % HG;
    int b   = tmp / HG;
    if (b >= B) return;

    const float* xb = x + (size_t)b * C * H * W + (size_t)(4 * hg) * W + 4 * wp;
    float s00 = 0.f, s01 = 0.f, s10 = 0.f, s11 = 0.f;
    #pragma unroll 4
    for (int c = 0; c < C; ++c) {
        const float* xc = xb + (size_t)c * (H * W);
        floatx4 r0 = __builtin_nontemporal_load(reinterpret_cast<const floatx4*>(xc));
        floatx4 r1 = __builtin_nontemporal_load(reinterpret_cast<const floatx4*>(xc + W));
        floatx4 r2 = __builtin_nontemporal_load(reinterpret_cast<const floatx4*>(xc + 2 * W));
        floatx4 r3 = __builtin_nontemporal_load(reinterpret_cast<const floatx4*>(xc + 3 * W));
        s00 += (r0.x + r0.y) + (r1.x + r1.y);
        s01 += (r0.z + r0.w) + (r1.z + r1.w);
        s10 += (r2.x + r2.y) + (r3.x + r3.y);
        s11 += (r2.z + r2.w) + (r3.z + r3.w);
    }
    float* pb = pooled + (size_t)b * HO * WO + (size_t)(2 * hg) * WO + 2 * wp;
    *reinterpret_cast<float2*>(pb)      = make_float2(s00, s01);
    *reinterpret_cast<float2*>(pb + WO) = make_float2(s10, s11);
}

__global__ __launch_bounds__(256) void broadcast_affine_kernel(
    const float* __restrict__ pooled,
    const float* __restrict__ coef,
    const float* __restrict__ bias,
    float* __restrict__ out)
{
    const size_t nvec   = (size_t)B * C * HO * (WO / 4);
    const size_t stride = (size_t)gridDim.x * blockDim.x;
    for (size_t i = blockIdx.x * (size_t)blockDim.x + threadIdx.x;
         i < nvec; i += stride) {
        int wq = (int)(i & 31);
        int ho = (int)((i >> 5) & 127);
        int c  = (int)((i >> 12) & 63);
        int b  = (int)(i >> 18);
        floatx4 p = *reinterpret_cast<const floatx4*>(
            pooled + ((size_t)b * HO + ho) * WO + wq * 4);
        float k  = coef[c];
        float bs = bias[c];
        floatx4 v;
        v.x = fmaf(p.x, k, bs);
        v.y = fmaf(p.y, k, bs);
        v.z = fmaf(p.z, k, bs);
        v.w = fmaf(p.w, k, bs);
        __builtin_nontemporal_store(v, reinterpret_cast<floatx4*>(out + i * 4));
    }
}

// -------- Fused fallback (no usable ws) ------------------------------------
__global__ __launch_bounds__(256) void subsample_fused_kernel(
    const float* __restrict__ x,
    const float* __restrict__ coef,
    const float* __restrict__ bias,
    float* __restrict__ out)
{
    const int WO2 = WO / 2;
    const int HG  = HO / 2;
    int t   = blockIdx.x * blockDim.x + threadIdx.x;
    int wp  = t % WO2;
    int tmp = t / WO2;
    int hg  = tmp % HG;
    int b   = tmp / HG;
    if (b >= B) return;

    const float* xb = x + (size_t)b * C * H * W + (size_t)(4 * hg) * W + 4 * wp;
    float s00 = 0.f, s01 = 0.f, s10 = 0.f, s11 = 0.f;
    #pragma unroll 4
    for (int c = 0; c < C; ++c) {
        const float* xc = xb + (size_t)c * (H * W);
        floatx4 r0 = __builtin_nontemporal_load(reinterpret_cast<const floatx4*>(xc));
        floatx4 r1 = __builtin_nontemporal_load(reinterpret_cast<const floatx4*>(xc + W));
        floatx4 r2 = __builtin_nontemporal_load(reinterpret_cast<const floatx4*>(xc + 2 * W));
        floatx4 r3 = __builtin_nontemporal_load(reinterpret_cast<const floatx4*>(xc + 3 * W));
        s00 += (r0.x + r0.y) + (r1.x + r1.y);
        s01 += (r0.z + r0.w) + (r1.z + r1.w);
        s10 += (r2.x + r2.y) + (r3.x + r3.y);
        s11 += (r2.z + r2.w) + (r3.z + r3.w);
    }
    float* ob = out + (size_t)b * C * HO * WO + (size_t)(2 * hg) * WO + 2 * wp;
    #pragma unroll 8
    for (int c = 0; c < C; ++c) {
        float k = coef[c], bs = bias[c];
        float* o0 = ob + (size_t)c * (HO * WO);
        *reinterpret_cast<float2*>(o0)      = make_float2(fmaf(s00, k, bs), fmaf(s01, k, bs));
        *reinterpret_cast<float2*>(o0 + WO) = make_float2(fmaf(s10, k, bs), fmaf(s11, k, bs));
    }
}

extern "C" void kernel_launch(void* const* d_in, const int* in_sizes, int n_in,
                              void* d_out, int out_size, void* d_ws, size_t ws_size,
                              hipStream_t stream) {
    const float* x    = (const float*)d_in[0];
    const float* coef = (const float*)d_in[1];
    const float* bias = (const float*)d_in[2];
    float* out = (float*)d_out;

    const size_t pooled_bytes = (size_t)B * HO * WO * sizeof(float);  // 2 MiB

    if (d_ws != nullptr && ws_size >= G * pooled_bytes) {
        float* pooled = (float*)d_ws;
        // Pass 1: 524,288 threads = 2048 blocks (8 blocks/CU, 32 waves/CU)
        const int total1 = B * G * (HO / 2) * (WO / 2);
        pool_reduce_split_kernel<<<total1 / 256, 256, 0, stream>>>(x, pooled);
        // Pass 2: grid-stride, 2048 blocks, slab-sequential NT writes
        broadcast_affine4_kernel<<<2048, 256, 0, stream>>>(pooled, coef, bias, out);
    } else if (d_ws != nullptr && ws_size >= pooled_bytes) {
        float* pooled = (float*)d_ws;
        const int total1 = B * (HO / 2) * (WO / 2);
        pool_reduce_kernel<<<total1 / 256, 256, 0, stream>>>(x, pooled);
        broadcast_affine_kernel<<<2048, 256, 0, stream>>>(pooled, coef, bias, out);
    } else {
        const int total = B * (HO / 2) * (WO / 2);
        subsample_fused_kernel<<<total / 256, 256, 0, stream>>>(x, coef, bias, out);
    }
}

// Round 9
// 109.458 us; speedup vs baseline: 1.0916x; 1.0916x over previous
//
#include <hip/hip_runtime.h>

// Problem constants (from reference):
//   x:    [32, 64, 256, 256] fp32
//   coef: [64,1,1] fp32, bias: [64,1,1] fp32 (zeros)
//   out:  [32, 64, 128, 128] fp32
// out[b,c,ho,wo] = coef[c] * sum_{c'} sum_{2x2} x[b,c',2ho+dh,2wo+dw] + bias[c]
//
// FINAL (R7 config, proven 109.7 us): two-pass split.
//   pass 1: x (512 MiB, NT loads) -> G=2 channel-group partials in d_ws
//           (1024 blocks = 16 waves/CU -- the measured occupancy sweet spot:
//            8 waves/CU = 113.8us, 16 = 109.7us, 32 = 119.5us)
//   pass 2: grid-stride broadcast (slab-sequential NT writes), summing the
//           2 L2-resident partials.
// Ladder: 138.0 (fused) -> 128.6 (NT) -> 122.4 (2-row) -> 113.8 (2-pass)
//         -> 109.7 (G=2) -> 119.5 (G=4, reverted).
// Floor ~100-104 us (537 MB read + 134 MB write at 6.6-6.9 TB/s pure-stream).

constexpr int B  = 32;
constexpr int C  = 64;
constexpr int H  = 256;
constexpr int W  = 256;
constexpr int HO = 128;
constexpr int WO = 128;

constexpr int G   = 2;       // channel groups for pass 1 (measured optimum)
constexpr int CPG = C / G;   // 32 channels per group

typedef float floatx4 __attribute__((ext_vector_type(4)));

// -------- Pass 1 (split): channel-group sum + 2x2 pool (pure read) ---------
__global__ __launch_bounds__(256) void pool_reduce_split_kernel(
    const float* __restrict__ x,
    float* __restrict__ pooled)   // [G][B, HO, WO]
{
    // Thread handles a 2x2 block of pooled pixels for ONE channel group.
    const int WO2 = WO / 2;   // 64
    const int HG  = HO / 2;   // 64

    int t    = blockIdx.x * blockDim.x + threadIdx.x;
    int wp   = t % WO2;
    int tmp  = t / WO2;       // hg + HG*(g + G*b)
    int hg   = tmp % HG;
    int tmp2 = tmp / HG;
    int g    = tmp2 % G;
    int b    = tmp2 / G;
    if (b >= B) return;

    const float* xb = x + (size_t)b * C * H * W + (size_t)(g * CPG) * H * W
                        + (size_t)(4 * hg) * W + 4 * wp;

    float s00 = 0.f, s01 = 0.f;
    float s10 = 0.f, s11 = 0.f;
    #pragma unroll 4
    for (int c = 0; c < CPG; ++c) {
        const float* xc = xb + (size_t)c * (H * W);
        floatx4 r0 = __builtin_nontemporal_load(reinterpret_cast<const floatx4*>(xc));
        floatx4 r1 = __builtin_nontemporal_load(reinterpret_cast<const floatx4*>(xc + W));
        floatx4 r2 = __builtin_nontemporal_load(reinterpret_cast<const floatx4*>(xc + 2 * W));
        floatx4 r3 = __builtin_nontemporal_load(reinterpret_cast<const floatx4*>(xc + 3 * W));
        s00 += (r0.x + r0.y) + (r1.x + r1.y);
        s01 += (r0.z + r0.w) + (r1.z + r1.w);
        s10 += (r2.x + r2.y) + (r3.x + r3.y);
        s11 += (r2.z + r2.w) + (r3.z + r3.w);
    }

    float* pb = pooled + (size_t)g * B * HO * WO + (size_t)b * HO * WO
                       + (size_t)(2 * hg) * WO + 2 * wp;
    *reinterpret_cast<float2*>(pb)      = make_float2(s00, s01);
    *reinterpret_cast<float2*>(pb + WO) = make_float2(s10, s11);
}

// -------- Pass 2: grid-stride broadcast + affine (pure write) --------------
__global__ __launch_bounds__(256) void broadcast_affine2_kernel(
    const float* __restrict__ pooled,  // [G][B, HO, WO], L2/L3-resident
    const float* __restrict__ coef,
    const float* __restrict__ bias,
    float* __restrict__ out)           // [B, C, HO, WO]
{
    // Flat vec index i maps exactly to out layout; each grid-stride sweep
    // writes a contiguous slab of out (slab-sequential DRAM writes).
    const size_t nvec   = (size_t)B * C * HO * (WO / 4);    // 8,388,608
    const size_t stride = (size_t)gridDim.x * blockDim.x;
    const float* pooled1 = pooled + (size_t)B * HO * WO;

    for (size_t i = blockIdx.x * (size_t)blockDim.x + threadIdx.x;
         i < nvec; i += stride) {
        int wq = (int)(i & 31);          // WO/4 = 32
        int ho = (int)((i >> 5) & 127);  // HO = 128
        int c  = (int)((i >> 12) & 63);  // C = 64
        int b  = (int)(i >> 18);

        size_t sp = ((size_t)b * HO + ho) * WO + wq * 4;
        floatx4 pa = *reinterpret_cast<const floatx4*>(pooled  + sp);
        floatx4 pb = *reinterpret_cast<const floatx4*>(pooled1 + sp);
        float k  = coef[c];
        float bs = bias[c];
        floatx4 v;
        v.x = fmaf(pa.x + pb.x, k, bs);
        v.y = fmaf(pa.y + pb.y, k, bs);
        v.z = fmaf(pa.z + pb.z, k, bs);
        v.w = fmaf(pa.w + pb.w, k, bs);
        __builtin_nontemporal_store(v, reinterpret_cast<floatx4*>(out + i * 4));
    }
}

// -------- Single-buffer path (if ws in [2 MiB, 4 MiB)) ---------------------
__global__ __launch_bounds__(256) void pool_reduce_kernel(
    const float* __restrict__ x,
    float* __restrict__ pooled)   // [B, HO, WO]
{
    const int WO2 = WO / 2;
    const int HG  = HO / 2;
    int t   = blockIdx.x * blockDim.x + threadIdx.x;
    int wp  = t % WO2;
    int tmp = t / WO2;
    int hg  = tmp % HG;
    int b   = tmp / HG;
    if (b >= B) return;

    const float* xb = x + (size_t)b * C * H * W + (size_t)(4 * hg) * W + 4 * wp;
    float s00 = 0.f, s01 = 0.f, s10 = 0.f, s11 = 0.f;
    #pragma unroll 4
    for (int c = 0; c < C; ++c) {
        const float* xc = xb + (size_t)c * (H * W);
        floatx4 r0 = __builtin_nontemporal_load(reinterpret_cast<const floatx4*>(xc));
        floatx4 r1 = __builtin_nontemporal_load(reinterpret_cast<const floatx4*>(xc + W));
        floatx4 r2 = __builtin_nontemporal_load(reinterpret_cast<const floatx4*>(xc + 2 * W));
        floatx4 r3 = __builtin_nontemporal_load(reinterpret_cast<const floatx4*>(xc + 3 * W));
        s00 += (r0.x + r0.y) + (r1.x + r1.y);
        s01 += (r0.z + r0.w) + (r1.z + r1.w);
        s10 += (r2.x + r2.y) + (r3.x + r3.y);
        s11 += (r2.z + r2.w) + (r3.z + r3.w);
    }
    float* pb = pooled + (size_t)b * HO * WO + (size_t)(2 * hg) * WO + 2 * wp;
    *reinterpret_cast<float2*>(pb)      = make_float2(s00, s01);
    *reinterpret_cast<float2*>(pb + WO) = make_float2(s10, s11);
}

__global__ __launch_bounds__(256) void broadcast_affine_kernel(
    const float* __restrict__ pooled,
    const float* __restrict__ coef,
    const float* __restrict__ bias,
    float* __restrict__ out)
{
    const size_t nvec   = (size_t)B * C * HO * (WO / 4);
    const size_t stride = (size_t)gridDim.x * blockDim.x;
    for (size_t i = blockIdx.x * (size_t)blockDim.x + threadIdx.x;
         i < nvec; i += stride) {
        int wq = (int)(i & 31);
        int ho = (int)((i >> 5) & 127);
        int c  = (int)((i >> 12) & 63);
        int b  = (int)(i >> 18);
        floatx4 p = *reinterpret_cast<const floatx4*>(
            pooled + ((size_t)b * HO + ho) * WO + wq * 4);
        float k  = coef[c];
        float bs = bias[c];
        floatx4 v;
        v.x = fmaf(p.x, k, bs);
        v.y = fmaf(p.y, k, bs);
        v.z = fmaf(p.z, k, bs);
        v.w = fmaf(p.w, k, bs);
        __builtin_nontemporal_store(v, reinterpret_cast<floatx4*>(out + i * 4));
    }
}

// -------- Fused fallback (no usable ws) ------------------------------------
__global__ __launch_bounds__(256) void subsample_fused_kernel(
    const float* __restrict__ x,
    const float* __restrict__ coef,
    const float* __restrict__ bias,
    float* __restrict__ out)
{
    const int WO2 = WO / 2;
    const int HG  = HO / 2;
    int t   = blockIdx.x * blockDim.x + threadIdx.x;
    int wp  = t % WO2;
    int tmp = t / WO2;
    int hg  = tmp % HG;
    int b   = tmp / HG;
    if (b >= B) return;

    const float* xb = x + (size_t)b * C * H * W + (size_t)(4 * hg) * W + 4 * wp;
    float s00 = 0.f, s01 = 0.f, s10 = 0.f, s11 = 0.f;
    #pragma unroll 4
    for (int c = 0; c < C; ++c) {
        const float* xc = xb + (size_t)c * (H * W);
        floatx4 r0 = __builtin_nontemporal_load(reinterpret_cast<const floatx4*>(xc));
        floatx4 r1 = __builtin_nontemporal_load(reinterpret_cast<const floatx4*>(xc + W));
        floatx4 r2 = __builtin_nontemporal_load(reinterpret_cast<const floatx4*>(xc + 2 * W));
        floatx4 r3 = __builtin_nontemporal_load(reinterpret_cast<const floatx4*>(xc + 3 * W));
        s00 += (r0.x + r0.y) + (r1.x + r1.y);
        s01 += (r0.z + r0.w) + (r1.z + r1.w);
        s10 += (r2.x + r2.y) + (r3.x + r3.y);
        s11 += (r2.z + r2.w) + (r3.z + r3.w);
    }
    float* ob = out + (size_t)b * C * HO * WO + (size_t)(2 * hg) * WO + 2 * wp;
    #pragma unroll 8
    for (int c = 0; c < C; ++c) {
        float k = coef[c], bs = bias[c];
        float* o0 = ob + (size_t)c * (HO * WO);
        *reinterpret_cast<float2*>(o0)      = make_float2(fmaf(s00, k, bs), fmaf(s01, k, bs));
        *reinterpret_cast<float2*>(o0 + WO) = make_float2(fmaf(s10, k, bs), fmaf(s11, k, bs));
    }
}

extern "C" void kernel_launch(void* const* d_in, const int* in_sizes, int n_in,
                              void* d_out, int out_size, void* d_ws, size_t ws_size,
                              hipStream_t stream) {
    const float* x    = (const float*)d_in[0];
    const float* coef = (const float*)d_in[1];
    const float* bias = (const float*)d_in[2];
    float* out = (float*)d_out;

    const size_t pooled_bytes = (size_t)B * HO * WO * sizeof(float);  // 2 MiB

    if (d_ws != nullptr && ws_size >= G * pooled_bytes) {
        float* pooled = (float*)d_ws;
        // Pass 1: 262,144 threads = 1024 blocks (4 blocks/CU, 16 waves/CU)
        const int total1 = B * G * (HO / 2) * (WO / 2);
        pool_reduce_split_kernel<<<total1 / 256, 256, 0, stream>>>(x, pooled);
        // Pass 2: grid-stride, 2048 blocks, slab-sequential NT writes
        broadcast_affine2_kernel<<<2048, 256, 0, stream>>>(pooled, coef, bias, out);
    } else if (d_ws != nullptr && ws_size >= pooled_bytes) {
        float* pooled = (float*)d_ws;
        const int total1 = B * (HO / 2) * (WO / 2);
        pool_reduce_kernel<<<total1 / 256, 256, 0, stream>>>(x, pooled);
        broadcast_affine_kernel<<<2048, 256, 0, stream>>>(pooled, coef, bias, out);
    } else {
        const int total = B * (HO / 2) * (WO / 2);
        subsample_fused_kernel<<<total / 256, 256, 0, stream>>>(x, coef, bias, out);
    }
}